// Round 2
// baseline (12110.189 us; speedup 1.0000x reference)
//
#include <hip/hip_runtime.h>
#include <hip/hip_bf16.h>

// Problem sizes (fixed)
#define BB 32
#define TT 512
#define HH 1024
#define II 1024
#define G4H 4096
#define BH  (BB * HH)          // 32768

typedef __bf16 bf16x8_t __attribute__((ext_vector_type(8)));
typedef float f32x4_t __attribute__((ext_vector_type(4)));

// ---------------------------------------------------------------------------
// Zero the rotating h buffers + barrier counter. (ws re-poisoned 0xAA each call)
// grid: 256 x 256 covers 65536 = 2*BH
// ---------------------------------------------------------------------------
__global__ void init_bufs(__hip_bfloat16* __restrict__ h0buf,
                          __hip_bfloat16* __restrict__ h1buf,
                          unsigned* __restrict__ cnt) {
    int i = blockIdx.x * 256 + threadIdx.x;
    h0buf[i] = __float2bfloat16(0.f);
    h1buf[i] = __float2bfloat16(0.f);
    if (i == 0) *cnt = 0u;
}

// ---------------------------------------------------------------------------
// Weight shuffle: fp32 [4096][1024] -> bf16 B-fragment order for the persistent
// kernel. Flat dst index bits: jj:3 | lane:6 | kb:4 | kh:1 | tau:1 | hg:7
//   n = lane&15, q = lane>>4
//   row = (2*tau + (n>>3))*1024 + hg*8 + (n&7)     (tau: gates {i,f} / {g,o})
//   col = kh*512 + kb*32 + q*8 + jj
// Hot-loop B loads become lane-consecutive 16B chunks (perfectly coalesced).
// ---------------------------------------------------------------------------
__global__ void shuffle_w(const float* __restrict__ src, __hip_bfloat16* __restrict__ dst) {
    size_t i = (size_t)blockIdx.x * 256 + threadIdx.x;   // 0 .. 4M-1
    int jj   = (int)(i & 7);
    int lane = (int)((i >> 3) & 63);
    int kb   = (int)((i >> 9) & 15);
    int kh   = (int)((i >> 13) & 1);
    int tau  = (int)((i >> 14) & 1);
    int hg   = (int)(i >> 15);
    int n = lane & 15, q = lane >> 4;
    int row = (2 * tau + (n >> 3)) * 1024 + hg * 8 + (n & 7);
    int col = kh * 512 + kb * 32 + q * 8 + jj;
    dst[i] = __float2bfloat16(src[(size_t)row * II + col]);
}

// ---------------------------------------------------------------------------
// x [B][T][I] fp32 -> xb [T][B][I] bf16
// ---------------------------------------------------------------------------
__global__ void convert_x(const float* __restrict__ x, __hip_bfloat16* __restrict__ xb) {
    size_t i = (size_t)blockIdx.x * 256 + threadIdx.x;   // T*B*I
    int ii = (int)(i & 1023);
    int b  = (int)((i >> 10) & 31);
    int t  = (int)(i >> 15);
    xb[i] = __float2bfloat16(x[((size_t)b * TT + t) * II + ii]);
}

// ---------------------------------------------------------------------------
// Persistent fused 2-layer LSTM. 256 WGs (1/CU) x 512 threads (8 waves).
// WG wg: bh = wg>>7 (batch half, 16 batches), hg = wg&127 (8 h-dims -> 32 gate rows).
// wave w: L = w>>2 (layer), p = (w>>1)&1 (0: x-GEMM, 1: h-GEMM), kh = w&1 (K half).
// Each wave holds its 32 B-fragments (32 rows x 512 K) permanently in VGPRs.
// Skewed pipeline: phase t runs layer0@t and layer1@(t-1). 513 phases, global
// barrier (atomic counter + threadfence) between phases.
// c-state lives in a register of its pointwise thread; residual h0 via LDS fp32.
// ---------------------------------------------------------------------------
__global__ __launch_bounds__(512, 2)
void lstm_persist(const __hip_bfloat16* __restrict__ xb,
                  const __hip_bfloat16* __restrict__ Wxs0, const __hip_bfloat16* __restrict__ Whs0,
                  const __hip_bfloat16* __restrict__ Wxs1, const __hip_bfloat16* __restrict__ Whs1,
                  const float* __restrict__ bih0, const float* __restrict__ bhh0,
                  const float* __restrict__ bih1, const float* __restrict__ bhh1,
                  __hip_bfloat16* __restrict__ h0buf,   // [2][BH] rotating
                  __hip_bfloat16* __restrict__ h1buf,   // [2][BH] rotating
                  float* __restrict__ out,              // [B][T][H]
                  unsigned* __restrict__ cnt)
{
    const int wg = blockIdx.x, tid = threadIdx.x;
    const int bh = wg >> 7, hg = wg & 127;
    const int wave = tid >> 6, lane = tid & 63;
    const int L = wave >> 2, p = (wave >> 1) & 1, kh = wave & 1;
    const int n = lane & 15, q = lane >> 4;

    __shared__ float psum[2][2][2][16][33];   // [L][p][kh][batch][tau*16+n], +1 pad
    __shared__ float res[2][128];             // fp32 h0 hand-off for the residual

    // ---- B-fragments into registers: 32 x bf16x8 = 128 VGPRs, loaded once ----
    const __hip_bfloat16* Wsel = L ? (p ? Whs1 : Wxs1) : (p ? Whs0 : Wxs0);
    const __bf16* wb = (const __bf16*)Wsel;
    bf16x8_t Breg[32];
#pragma unroll
    for (int tau = 0; tau < 2; ++tau)
#pragma unroll
        for (int kb = 0; kb < 16; ++kb)
            Breg[tau * 16 + kb] =
                *(const bf16x8_t*)(wb + ((((((size_t)hg * 2 + tau) * 2 + kh) * 16) + kb) * 64 + lane) * 8);

    // ---- pointwise thread state (threads 0..255): biases in regs, c in a reg ----
    const int pw_L = tid >> 7, pw_idx = tid & 127, pw_b = (tid >> 3) & 15, pw_d = tid & 7;
    float bias_r[4] = {0.f, 0.f, 0.f, 0.f};
    float c_reg = 0.f;
    if (tid < 256) {
        const float* bi = pw_L ? bih1 : bih0;
        const float* bh2 = pw_L ? bhh1 : bhh0;
#pragma unroll
        for (int g = 0; g < 4; ++g) {
            int row = g * 1024 + hg * 8 + pw_d;
            bias_r[g] = bi[row] + bh2[row];
        }
    }

    const int arow = bh * 16 + n;

    for (int t = 0; t <= TT; ++t) {
        // ---- A-operand select for this wave's GEMM ----
        const __hip_bfloat16* Abuf;
        if (L == 0) {
            // layer0 @ t: x(t), h0(t-1)
            Abuf = p ? (h0buf + (size_t)((t + 1) & 1) * BH)
                     : (xb + (size_t)(t < TT ? t : TT - 1) * BH);
        } else {
            // layer1 @ t-1: h0(t-1), h1(t-2)
            Abuf = p ? (h1buf + (size_t)(t & 1) * BH)
                     : (h0buf + (size_t)((t + 1) & 1) * BH);
        }
        const __bf16* a_base = (const __bf16*)Abuf + arow * 1024 + kh * 512 + q * 8;

        f32x4_t acc0 = {0.f, 0.f, 0.f, 0.f};
        f32x4_t acc1 = {0.f, 0.f, 0.f, 0.f};
#pragma unroll
        for (int kb = 0; kb < 16; ++kb) {
            bf16x8_t av = *(const bf16x8_t*)(a_base + kb * 32);
            acc0 = __builtin_amdgcn_mfma_f32_16x16x32_bf16(av, Breg[kb], acc0, 0, 0, 0);
            acc1 = __builtin_amdgcn_mfma_f32_16x16x32_bf16(av, Breg[16 + kb], acc1, 0, 0, 0);
        }
        // C/D: lane holds D[i = q*4+r][j = n]
#pragma unroll
        for (int r = 0; r < 4; ++r) {
            psum[L][p][kh][q * 4 + r][n] = acc0[r];
            psum[L][p][kh][q * 4 + r][16 + n] = acc1[r];
        }
        __syncthreads();

        // ---- pointwise: gates -> c,h; layer0 writes h0+res, layer1 writes h1+out ----
        if (tid < 256) {
            const bool active = pw_L ? (t >= 1) : (t < TT);
            if (active) {
                float gv[4];
#pragma unroll
                for (int g = 0; g < 4; ++g) {
                    int col = (g >> 1) * 16 + (g & 1) * 8 + pw_d;
                    gv[g] = psum[pw_L][0][0][pw_b][col] + psum[pw_L][0][1][pw_b][col]
                          + psum[pw_L][1][0][pw_b][col] + psum[pw_L][1][1][pw_b][col]
                          + bias_r[g];
                }
                float si = 1.f / (1.f + __expf(-gv[0]));
                float sf = 1.f / (1.f + __expf(-gv[1]));
                float tg = 2.f / (1.f + __expf(-2.f * gv[2])) - 1.f;
                float so = 1.f / (1.f + __expf(-gv[3]));
                c_reg = sf * c_reg + si * tg;
                float hv = so * (2.f / (1.f + __expf(-2.f * c_reg)) - 1.f);
                const int gidx = (bh * 16 + pw_b) * 1024 + hg * 8 + pw_d;
                if (pw_L == 0) {
                    h0buf[(size_t)(t & 1) * BH + gidx] = __float2bfloat16(hv);
                    res[t & 1][pw_idx] = hv;                     // fp32 residual hand-off
                } else {
                    h1buf[(size_t)((t - 1) & 1) * BH + gidx] = __float2bfloat16(hv);
                    out[(size_t)(bh * 16 + pw_b) * TT * HH + (size_t)(t - 1) * HH + hg * 8 + pw_d]
                        = res[(t + 1) & 1][pw_idx] + hv;
                }
            }
        }
        __syncthreads();   // psum reads done + all global stores vmcnt-drained

        // ---- global barrier (skip after final phase) ----
        if (t < TT) {
            if (tid == 0) {
                __threadfence();   // release: flush this XCD's L2 to coherence point
                __hip_atomic_fetch_add(cnt, 1u, __ATOMIC_RELAXED, __HIP_MEMORY_SCOPE_AGENT);
                const unsigned tgt = 256u * (unsigned)(t + 1);
                while (__hip_atomic_load(cnt, __ATOMIC_RELAXED, __HIP_MEMORY_SCOPE_AGENT) < tgt)
                    __builtin_amdgcn_s_sleep(1);
                __threadfence();   // acquire: invalidate L1/L2 before reading fresh h
            }
            __syncthreads();
        }
    }
}

// ---------------------------------------------------------------------------
// Host side
// ---------------------------------------------------------------------------
extern "C" void kernel_launch(void* const* d_in, const int* in_sizes, int n_in,
                              void* d_out, int out_size, void* d_ws, size_t ws_size,
                              hipStream_t stream) {
    const float* x    = (const float*)d_in[0];
    const float* Wih0 = (const float*)d_in[1];
    const float* Whh0 = (const float*)d_in[2];
    const float* bih0 = (const float*)d_in[3];
    const float* bhh0 = (const float*)d_in[4];
    const float* Wih1 = (const float*)d_in[5];
    const float* Whh1 = (const float*)d_in[6];
    const float* bih1 = (const float*)d_in[7];
    const float* bhh1 = (const float*)d_in[8];
    float* out = (float*)d_out;
    (void)in_sizes; (void)n_in; (void)out_size; (void)ws_size;

    // Workspace carve (~67.3 MiB)
    uint8_t* w = (uint8_t*)d_ws;
    const size_t WMAT = (size_t)G4H * HH * 2;   // 8 MiB bf16 per matrix
    __hip_bfloat16* Wxs0 = (__hip_bfloat16*)(w);
    __hip_bfloat16* Whs0 = (__hip_bfloat16*)(w + WMAT);
    __hip_bfloat16* Wxs1 = (__hip_bfloat16*)(w + 2 * WMAT);
    __hip_bfloat16* Whs1 = (__hip_bfloat16*)(w + 3 * WMAT);
    size_t off = 4 * WMAT;
    __hip_bfloat16* xbuf = (__hip_bfloat16*)(w + off); off += (size_t)TT * BB * II * 2;
    __hip_bfloat16* h0buf = (__hip_bfloat16*)(w + off); off += 2 * (size_t)BH * 2;
    __hip_bfloat16* h1buf = (__hip_bfloat16*)(w + off); off += 2 * (size_t)BH * 2;
    unsigned* cnt = (unsigned*)(w + off); off += 256;

    init_bufs<<<(2 * BH) / 256, 256, 0, stream>>>(h0buf, h1buf, cnt);
    shuffle_w<<<(G4H * HH) / 256, 256, 0, stream>>>(Wih0, Wxs0);
    shuffle_w<<<(G4H * HH) / 256, 256, 0, stream>>>(Whh0, Whs0);
    shuffle_w<<<(G4H * HH) / 256, 256, 0, stream>>>(Wih1, Wxs1);
    shuffle_w<<<(G4H * HH) / 256, 256, 0, stream>>>(Whh1, Whs1);
    convert_x<<<(TT * BB * II) / 256, 256, 0, stream>>>(x, xbuf);

    lstm_persist<<<256, 512, 0, stream>>>(xbuf, Wxs0, Whs0, Wxs1, Whs1,
                                          bih0, bhh0, bih1, bhh1,
                                          h0buf, h1buf, out, cnt);
}

// Round 3
// 5740.924 us; speedup vs baseline: 2.1094x; 2.1094x over previous
//
#include <hip/hip_runtime.h>
#include <hip/hip_bf16.h>

// Problem sizes (fixed)
#define BB 32
#define TT 512
#define HH 1024
#define II 1024
#define G4H 4096
#define BH  (BB * HH)          // 32768

typedef __bf16 bf16x8_t __attribute__((ext_vector_type(8)));
typedef float f32x4_t __attribute__((ext_vector_type(4)));
typedef int i32x4_t __attribute__((ext_vector_type(4)));
typedef unsigned long long u64;

// ---------------------------------------------------------------------------
// Zero rotating h buffers, barrier counter, go flags. (ws re-poisoned 0xAA)
// grid: 256 x 256 covers 65536 = 2*BH
// ---------------------------------------------------------------------------
__global__ void init_bufs(__hip_bfloat16* __restrict__ h0buf,
                          __hip_bfloat16* __restrict__ h1buf,
                          unsigned* __restrict__ cnt,
                          unsigned* __restrict__ go) {
    int i = blockIdx.x * 256 + threadIdx.x;
    h0buf[i] = __float2bfloat16(0.f);
    h1buf[i] = __float2bfloat16(0.f);
    if (i < 4096) go[i] = 0u;
    if (i == 0) *cnt = 0u;
}

// ---------------------------------------------------------------------------
// Weight shuffle: fp32 [4096][1024] -> bf16 B-fragment order.
// dst bits: jj:3 | lane:6 | kb:4 | kh:1 | tau:1 | hg:7
//   n=lane&15, q=lane>>4
//   row = (2*tau + (n>>3))*1024 + hg*8 + (n&7)
//   col = kh*512 + kb*32 + q*8 + jj
// ---------------------------------------------------------------------------
__global__ void shuffle_w(const float* __restrict__ src, __hip_bfloat16* __restrict__ dst) {
    size_t i = (size_t)blockIdx.x * 256 + threadIdx.x;   // 0 .. 4M-1
    int jj   = (int)(i & 7);
    int lane = (int)((i >> 3) & 63);
    int kb   = (int)((i >> 9) & 15);
    int kh   = (int)((i >> 13) & 1);
    int tau  = (int)((i >> 14) & 1);
    int hg   = (int)(i >> 15);
    int n = lane & 15, q = lane >> 4;
    int row = (2 * tau + (n >> 3)) * 1024 + hg * 8 + (n & 7);
    int col = kh * 512 + kb * 32 + q * 8 + jj;
    dst[i] = __float2bfloat16(src[(size_t)row * II + col]);
}

// ---------------------------------------------------------------------------
// x [B][T][I] fp32 -> xb [T][B][I] bf16
// ---------------------------------------------------------------------------
__global__ void convert_x(const float* __restrict__ x, __hip_bfloat16* __restrict__ xb) {
    size_t i = (size_t)blockIdx.x * 256 + threadIdx.x;   // T*B*I
    int ii = (int)(i & 1023);
    int b  = (int)((i >> 10) & 31);
    int t  = (int)(i >> 15);
    xb[i] = __float2bfloat16(x[((size_t)b * TT + t) * II + ii]);
}

// ---------------------------------------------------------------------------
// Persistent fused 2-layer LSTM. 256 WGs (1/CU) x 512 threads (8 waves).
// WG wg: bh = wg>>7 (batch half), hg = wg&127 (8 h-dims -> 32 gate rows).
// wave: L = w>>2 (layer), p = (w>>1)&1 (x- vs h-GEMM), kh = w&1 (K half).
// Weights pinned in VGPRs via empty-asm "+v" (32 x i32x4 = 128 VGPRs).
// Cross-WG traffic (h bufs, barrier) ONLY via agent-scope relaxed atomics:
// no threadfence -> no wbl2/inv -> L2-cached weights/x stay hot.
// Barrier: arrive counter (1 add/WG), single master poller, padded per-WG
// go flags (each non-master WG polls its OWN 64B line).
// ---------------------------------------------------------------------------
__global__ __launch_bounds__(512, 2)
void lstm_persist(const __hip_bfloat16* __restrict__ xb,
                  const __hip_bfloat16* __restrict__ Wxs0, const __hip_bfloat16* __restrict__ Whs0,
                  const __hip_bfloat16* __restrict__ Wxs1, const __hip_bfloat16* __restrict__ Whs1,
                  const float* __restrict__ bih0, const float* __restrict__ bhh0,
                  const float* __restrict__ bih1, const float* __restrict__ bhh1,
                  __hip_bfloat16* __restrict__ h0buf,   // [2][BH] rotating
                  __hip_bfloat16* __restrict__ h1buf,   // [2][BH] rotating
                  float* __restrict__ out,              // [B][T][H]
                  unsigned* __restrict__ cnt,
                  unsigned* __restrict__ go)            // [256][16] padded flags
{
    const int wg = blockIdx.x, tid = threadIdx.x;
    const int bh = wg >> 7, hg = wg & 127;
    const int wave = tid >> 6, lane = tid & 63;
    const int L = wave >> 2, p = (wave >> 1) & 1, kh = wave & 1;
    const int n = lane & 15, q = lane >> 4;

    __shared__ float psum[2][2][2][16][33];   // [L][p][kh][batch][tau*16+n]
    __shared__ float res[2][128];             // fp32 h0 hand-off for residual

    // ---- load B-fragments once, pin in registers ----
    const __hip_bfloat16* Wsel = L ? (p ? Whs1 : Wxs1) : (p ? Whs0 : Wxs0);
    const __bf16* wbp = (const __bf16*)Wsel;

    i32x4_t W0, W1, W2, W3, W4, W5, W6, W7, W8, W9, W10, W11, W12, W13, W14, W15,
            W16, W17, W18, W19, W20, W21, W22, W23, W24, W25, W26, W27, W28, W29, W30, W31;
#define LOADW(IDX, TAU, KB) \
    W##IDX = *(const i32x4_t*)(const void*)(wbp + ((((((size_t)hg * 2 + (TAU)) * 2 + kh) * 16) + (KB)) * 64 + lane) * 8)
    LOADW(0,0,0);  LOADW(1,0,1);  LOADW(2,0,2);  LOADW(3,0,3);
    LOADW(4,0,4);  LOADW(5,0,5);  LOADW(6,0,6);  LOADW(7,0,7);
    LOADW(8,0,8);  LOADW(9,0,9);  LOADW(10,0,10); LOADW(11,0,11);
    LOADW(12,0,12); LOADW(13,0,13); LOADW(14,0,14); LOADW(15,0,15);
    LOADW(16,1,0);  LOADW(17,1,1);  LOADW(18,1,2);  LOADW(19,1,3);
    LOADW(20,1,4);  LOADW(21,1,5);  LOADW(22,1,6);  LOADW(23,1,7);
    LOADW(24,1,8);  LOADW(25,1,9);  LOADW(26,1,10); LOADW(27,1,11);
    LOADW(28,1,12); LOADW(29,1,13); LOADW(30,1,14); LOADW(31,1,15);
#undef LOADW
    // Opaque-ify: forbids rematerializing these loads inside the phase loop.
    asm volatile("" : "+v"(W0), "+v"(W1), "+v"(W2), "+v"(W3),
                      "+v"(W4), "+v"(W5), "+v"(W6), "+v"(W7));
    asm volatile("" : "+v"(W8), "+v"(W9), "+v"(W10), "+v"(W11),
                      "+v"(W12), "+v"(W13), "+v"(W14), "+v"(W15));
    asm volatile("" : "+v"(W16), "+v"(W17), "+v"(W18), "+v"(W19),
                      "+v"(W20), "+v"(W21), "+v"(W22), "+v"(W23));
    asm volatile("" : "+v"(W24), "+v"(W25), "+v"(W26), "+v"(W27),
                      "+v"(W28), "+v"(W29), "+v"(W30), "+v"(W31));

    // ---- pointwise thread state (tid<256): biases in regs, c in a reg ----
    const int pw_L = tid >> 7, pw_idx = tid & 127, pw_b = (tid >> 3) & 15, pw_d = tid & 7;
    float bias_r[4] = {0.f, 0.f, 0.f, 0.f};
    float c_reg = 0.f;
    if (tid < 256) {
        const float* bi  = pw_L ? bih1 : bih0;
        const float* bh2 = pw_L ? bhh1 : bhh0;
#pragma unroll
        for (int g = 0; g < 4; ++g) {
            int row = g * 1024 + hg * 8 + pw_d;
            bias_r[g] = bi[row] + bh2[row];
        }
    }

    const int arow = bh * 16 + n;
    const bool coh = (L == 1) || (p == 1);   // h operands: coherent (IF-served) loads

#define MSTEP(AV, IA, IB) \
    acc0 = __builtin_amdgcn_mfma_f32_16x16x32_bf16(AV, __builtin_bit_cast(bf16x8_t, W##IA), acc0, 0, 0, 0); \
    acc1 = __builtin_amdgcn_mfma_f32_16x16x32_bf16(AV, __builtin_bit_cast(bf16x8_t, W##IB), acc1, 0, 0, 0)
#define CSTEP(KB, IA, IB) { \
    bf16x8_t av = *(const bf16x8_t*)(const void*)(a_base + (KB) * 32); \
    MSTEP(av, IA, IB); }
#define ASTEP(KB, IA, IB) { \
    union { u64 qq[2]; bf16x8_t v; } u_; \
    u64* ap = (u64*)(void*)(a_base + (KB) * 32); \
    u_.qq[0] = __hip_atomic_load(ap, __ATOMIC_RELAXED, __HIP_MEMORY_SCOPE_AGENT); \
    u_.qq[1] = __hip_atomic_load(ap + 1, __ATOMIC_RELAXED, __HIP_MEMORY_SCOPE_AGENT); \
    MSTEP(u_.v, IA, IB); }

    for (int t = 0; t <= TT; ++t) {
        // ---- A-operand select ----
        const __hip_bfloat16* Abuf;
        if (L == 0) {
            Abuf = p ? (h0buf + (size_t)((t + 1) & 1) * BH)
                     : (xb + (size_t)(t < TT ? t : TT - 1) * BH);
        } else {
            Abuf = p ? (h1buf + (size_t)(t & 1) * BH)
                     : (h0buf + (size_t)((t + 1) & 1) * BH);
        }
        const __bf16* a_base = (const __bf16*)Abuf + arow * 1024 + kh * 512 + q * 8;

        f32x4_t acc0 = {0.f, 0.f, 0.f, 0.f};
        f32x4_t acc1 = {0.f, 0.f, 0.f, 0.f};
        if (coh) {
            ASTEP(0,0,16);  ASTEP(1,1,17);  ASTEP(2,2,18);  ASTEP(3,3,19);
            ASTEP(4,4,20);  ASTEP(5,5,21);  ASTEP(6,6,22);  ASTEP(7,7,23);
            ASTEP(8,8,24);  ASTEP(9,9,25);  ASTEP(10,10,26); ASTEP(11,11,27);
            ASTEP(12,12,28); ASTEP(13,13,29); ASTEP(14,14,30); ASTEP(15,15,31);
        } else {
            CSTEP(0,0,16);  CSTEP(1,1,17);  CSTEP(2,2,18);  CSTEP(3,3,19);
            CSTEP(4,4,20);  CSTEP(5,5,21);  CSTEP(6,6,22);  CSTEP(7,7,23);
            CSTEP(8,8,24);  CSTEP(9,9,25);  CSTEP(10,10,26); CSTEP(11,11,27);
            CSTEP(12,12,28); CSTEP(13,13,29); CSTEP(14,14,30); CSTEP(15,15,31);
        }

        // C/D: lane holds D[i = q*4+r][j = n]
#pragma unroll
        for (int r = 0; r < 4; ++r) {
            psum[L][p][kh][q * 4 + r][n] = acc0[r];
            psum[L][p][kh][q * 4 + r][16 + n] = acc1[r];
        }
        __syncthreads();

        // ---- pointwise ----
        if (tid < 256) {
            const bool active = pw_L ? (t >= 1) : (t < TT);
            if (active) {
                float gv[4];
#pragma unroll
                for (int g = 0; g < 4; ++g) {
                    int col = (g >> 1) * 16 + (g & 1) * 8 + pw_d;
                    gv[g] = psum[pw_L][0][0][pw_b][col] + psum[pw_L][0][1][pw_b][col]
                          + psum[pw_L][1][0][pw_b][col] + psum[pw_L][1][1][pw_b][col]
                          + bias_r[g];
                }
                float si = 1.f / (1.f + __expf(-gv[0]));
                float sf = 1.f / (1.f + __expf(-gv[1]));
                float tg = 2.f / (1.f + __expf(-2.f * gv[2])) - 1.f;
                float so = 1.f / (1.f + __expf(-gv[3]));
                c_reg = sf * c_reg + si * tg;
                float hv = so * (2.f / (1.f + __expf(-2.f * c_reg)) - 1.f);
                const int gidx = (bh * 16 + pw_b) * 1024 + hg * 8 + pw_d;
                __hip_bfloat16 hb = __float2bfloat16(hv);
                unsigned short hraw;
                __builtin_memcpy(&hraw, &hb, 2);
                if (pw_L == 0) {
                    __hip_atomic_store((unsigned short*)&h0buf[(size_t)(t & 1) * BH + gidx],
                                       hraw, __ATOMIC_RELAXED, __HIP_MEMORY_SCOPE_AGENT);
                    res[t & 1][pw_idx] = hv;
                } else {
                    __hip_atomic_store((unsigned short*)&h1buf[(size_t)((t - 1) & 1) * BH + gidx],
                                       hraw, __ATOMIC_RELAXED, __HIP_MEMORY_SCOPE_AGENT);
                    out[(size_t)(bh * 16 + pw_b) * TT * HH + (size_t)(t - 1) * HH + hg * 8 + pw_d]
                        = res[(t + 1) & 1][pw_idx] + hv;
                }
            }
        }
        __syncthreads();   // drains vmcnt per-wave: h stores acked at IF before arrive

        // ---- global barrier (skip after final phase) ----
        if (t < TT) {
            if (tid == 0)
                __hip_atomic_fetch_add(cnt, 1u, __ATOMIC_RELAXED, __HIP_MEMORY_SCOPE_AGENT);
            if (wg == 0) {
                if (tid == 0) {
                    const unsigned tgt = 256u * (unsigned)(t + 1);
                    while (__hip_atomic_load(cnt, __ATOMIC_RELAXED, __HIP_MEMORY_SCOPE_AGENT) < tgt)
                        __builtin_amdgcn_s_sleep(1);
                }
                __syncthreads();
                if (tid < 256)
                    __hip_atomic_store(&go[tid * 16], (unsigned)(t + 1),
                                       __ATOMIC_RELAXED, __HIP_MEMORY_SCOPE_AGENT);
            } else {
                if (tid == 0) {
                    while (__hip_atomic_load(&go[wg * 16], __ATOMIC_RELAXED,
                                             __HIP_MEMORY_SCOPE_AGENT) < (unsigned)(t + 1))
                        __builtin_amdgcn_s_sleep(1);
                }
            }
            __syncthreads();
        }
    }
#undef MSTEP
#undef CSTEP
#undef ASTEP
}

// ---------------------------------------------------------------------------
// Host side
// ---------------------------------------------------------------------------
extern "C" void kernel_launch(void* const* d_in, const int* in_sizes, int n_in,
                              void* d_out, int out_size, void* d_ws, size_t ws_size,
                              hipStream_t stream) {
    const float* x    = (const float*)d_in[0];
    const float* Wih0 = (const float*)d_in[1];
    const float* Whh0 = (const float*)d_in[2];
    const float* bih0 = (const float*)d_in[3];
    const float* bhh0 = (const float*)d_in[4];
    const float* Wih1 = (const float*)d_in[5];
    const float* Whh1 = (const float*)d_in[6];
    const float* bih1 = (const float*)d_in[7];
    const float* bhh1 = (const float*)d_in[8];
    float* out = (float*)d_out;
    (void)in_sizes; (void)n_in; (void)out_size; (void)ws_size;

    // Workspace carve (~64.3 MiB)
    uint8_t* w = (uint8_t*)d_ws;
    const size_t WMAT = (size_t)G4H * HH * 2;   // 8 MiB bf16 per matrix
    __hip_bfloat16* Wxs0 = (__hip_bfloat16*)(w);
    __hip_bfloat16* Whs0 = (__hip_bfloat16*)(w + WMAT);
    __hip_bfloat16* Wxs1 = (__hip_bfloat16*)(w + 2 * WMAT);
    __hip_bfloat16* Whs1 = (__hip_bfloat16*)(w + 3 * WMAT);
    size_t off = 4 * WMAT;
    __hip_bfloat16* xbuf = (__hip_bfloat16*)(w + off); off += (size_t)TT * BB * II * 2;
    __hip_bfloat16* h0buf = (__hip_bfloat16*)(w + off); off += 2 * (size_t)BH * 2;
    __hip_bfloat16* h1buf = (__hip_bfloat16*)(w + off); off += 2 * (size_t)BH * 2;
    unsigned* cnt = (unsigned*)(w + off); off += 256;
    unsigned* go  = (unsigned*)(w + off); off += 4096 * 4;

    init_bufs<<<(2 * BH) / 256, 256, 0, stream>>>(h0buf, h1buf, cnt, go);
    shuffle_w<<<(G4H * HH) / 256, 256, 0, stream>>>(Wih0, Wxs0);
    shuffle_w<<<(G4H * HH) / 256, 256, 0, stream>>>(Whh0, Whs0);
    shuffle_w<<<(G4H * HH) / 256, 256, 0, stream>>>(Wih1, Wxs1);
    shuffle_w<<<(G4H * HH) / 256, 256, 0, stream>>>(Whh1, Whs1);
    convert_x<<<(TT * BB * II) / 256, 256, 0, stream>>>(x, xbuf);

    lstm_persist<<<256, 512, 0, stream>>>(xbuf, Wxs0, Whs0, Wxs1, Whs1,
                                          bih0, bhh0, bih1, bhh1,
                                          h0buf, h1buf, out, cnt, go);
}

// Round 4
// 4481.000 us; speedup vs baseline: 2.7026x; 1.2812x over previous
//
#include <hip/hip_runtime.h>
#include <hip/hip_bf16.h>

// Problem sizes (fixed)
#define BB 32
#define TT 512
#define HH 1024
#define II 1024
#define G4H 4096
#define BH  (BB * HH)          // 32768

typedef __bf16 bf16x8_t __attribute__((ext_vector_type(8)));
typedef float f32x4_t __attribute__((ext_vector_type(4)));
typedef int i32x4_t __attribute__((ext_vector_type(4)));
typedef unsigned long long u64;

// ---------------------------------------------------------------------------
// Zero rotating h buffers + arrive/go flag arrays. (ws re-poisoned 0xAA)
// grid: 256 x 256 covers 65536 = 2*BH
// ---------------------------------------------------------------------------
__global__ void init_bufs(__hip_bfloat16* __restrict__ h0buf,
                          __hip_bfloat16* __restrict__ h1buf,
                          unsigned* __restrict__ arr,
                          unsigned* __restrict__ go) {
    int i = blockIdx.x * 256 + threadIdx.x;
    h0buf[i] = __float2bfloat16(0.f);
    h1buf[i] = __float2bfloat16(0.f);
    if (i < 8192) { arr[i] = 0u; go[i] = 0u; }
}

// ---------------------------------------------------------------------------
// Weight shuffle: fp32 [4096][1024] -> bf16 B-fragment order.
// dst bits: jj:3 | lane:6 | kb:4 | kh:1 | tau:1 | hg:7
//   n=lane&15, q=lane>>4
//   row = (2*tau + (n>>3))*1024 + hg*8 + (n&7)
//   col = kh*512 + kb*32 + q*8 + jj
// ---------------------------------------------------------------------------
__global__ void shuffle_w(const float* __restrict__ src, __hip_bfloat16* __restrict__ dst) {
    size_t i = (size_t)blockIdx.x * 256 + threadIdx.x;   // 0 .. 4M-1
    int jj   = (int)(i & 7);
    int lane = (int)((i >> 3) & 63);
    int kb   = (int)((i >> 9) & 15);
    int kh   = (int)((i >> 13) & 1);
    int tau  = (int)((i >> 14) & 1);
    int hg   = (int)(i >> 15);
    int n = lane & 15, q = lane >> 4;
    int row = (2 * tau + (n >> 3)) * 1024 + hg * 8 + (n & 7);
    int col = kh * 512 + kb * 32 + q * 8 + jj;
    dst[i] = __float2bfloat16(src[(size_t)row * II + col]);
}

// ---------------------------------------------------------------------------
// x [B][T][I] fp32 -> xb [T][B][I] bf16
// ---------------------------------------------------------------------------
__global__ void convert_x(const float* __restrict__ x, __hip_bfloat16* __restrict__ xb) {
    size_t i = (size_t)blockIdx.x * 256 + threadIdx.x;   // T*B*I
    int ii = (int)(i & 1023);
    int b  = (int)((i >> 10) & 31);
    int t  = (int)(i >> 15);
    xb[i] = __float2bfloat16(x[((size_t)b * TT + t) * II + ii]);
}

// ---------------------------------------------------------------------------
// Persistent fused 2-layer LSTM. 256 WGs (1/CU) x 512 threads (8 waves).
// WG wg: bh = wg>>7 (batch half), hg = wg&127 (8 h-dims -> 32 gate rows).
// wave: L = w>>2 (layer), p = (w>>1)&1 (x- vs h-GEMM), kh = w&1 (K half).
// Weights pinned in VGPRs/AGPRs via empty-asm "+v" (32 x i32x4 per wave).
// Phase t = layer0@t + layer1@(t-1), skewed pipeline, 513 phases.
//
// Cross-WG data strictly via agent-scope relaxed atomics (cache-bypassing,
// no fences -> L2-cached weights/x stay hot).
//
// h0(t-1) is needed by BOTH L0-hGEMM (waves 2,3) and L1-xGEMM (waves 4,5):
// the four waves split the fabric load 8 steps each, stage through LDS,
// and all four consume from LDS (h0 fetched ONCE per WG). h1 waves (6,7)
// prefetch to regs before the stage barrier so fabric latency overlaps.
//
// Barrier: per-WG arrival STORES on private 128B lines (no RMW serialization);
// master WG's 256 threads poll all lines in parallel, then store per-WG go
// flags; each WG polls only its own go line.
// ---------------------------------------------------------------------------
__global__ __launch_bounds__(512, 2)
void lstm_persist(const __hip_bfloat16* __restrict__ xb,
                  const __hip_bfloat16* __restrict__ Wxs0, const __hip_bfloat16* __restrict__ Whs0,
                  const __hip_bfloat16* __restrict__ Wxs1, const __hip_bfloat16* __restrict__ Whs1,
                  const float* __restrict__ bih0, const float* __restrict__ bhh0,
                  const float* __restrict__ bih1, const float* __restrict__ bhh1,
                  __hip_bfloat16* __restrict__ h0buf,   // [2][BH] rotating
                  __hip_bfloat16* __restrict__ h1buf,   // [2][BH] rotating
                  float* __restrict__ out,              // [B][T][H]
                  unsigned* __restrict__ arr,           // [256][32] arrive flags
                  unsigned* __restrict__ go)            // [256][32] go flags
{
    const int wg = blockIdx.x, tid = threadIdx.x;
    const int bh = wg >> 7, hg = wg & 127;
    const int wave = tid >> 6, lane = tid & 63;
    const int L = wave >> 2, p = (wave >> 1) & 1, kh = wave & 1;
    const int n = lane & 15, q = lane >> 4;

    __shared__ float psum[2][2][2][16][37];   // [L][p][kh][batch][tau*16+n]; pad 37:
                                              // MFMA writes 2-way (free), pointwise reads conflict-free
    __shared__ float res[2][128];             // fp32 h0 hand-off for residual
    __shared__ u64 hstage[2][16][64][2];      // 32 KB: h0(t-1) fragments [kh][kb][lane]

    // ---- load B-fragments once, pin in registers ----
    const __hip_bfloat16* Wsel = L ? (p ? Whs1 : Wxs1) : (p ? Whs0 : Wxs0);
    const __bf16* wbp = (const __bf16*)Wsel;

    i32x4_t W0, W1, W2, W3, W4, W5, W6, W7, W8, W9, W10, W11, W12, W13, W14, W15,
            W16, W17, W18, W19, W20, W21, W22, W23, W24, W25, W26, W27, W28, W29, W30, W31;
#define LOADW(IDX, TAU, KB) \
    W##IDX = *(const i32x4_t*)(const void*)(wbp + ((((((size_t)hg * 2 + (TAU)) * 2 + kh) * 16) + (KB)) * 64 + lane) * 8)
    LOADW(0,0,0);  LOADW(1,0,1);  LOADW(2,0,2);  LOADW(3,0,3);
    LOADW(4,0,4);  LOADW(5,0,5);  LOADW(6,0,6);  LOADW(7,0,7);
    LOADW(8,0,8);  LOADW(9,0,9);  LOADW(10,0,10); LOADW(11,0,11);
    LOADW(12,0,12); LOADW(13,0,13); LOADW(14,0,14); LOADW(15,0,15);
    LOADW(16,1,0);  LOADW(17,1,1);  LOADW(18,1,2);  LOADW(19,1,3);
    LOADW(20,1,4);  LOADW(21,1,5);  LOADW(22,1,6);  LOADW(23,1,7);
    LOADW(24,1,8);  LOADW(25,1,9);  LOADW(26,1,10); LOADW(27,1,11);
    LOADW(28,1,12); LOADW(29,1,13); LOADW(30,1,14); LOADW(31,1,15);
#undef LOADW
    // Opaque-ify: forbids rematerializing these loads inside the phase loop.
    asm volatile("" : "+v"(W0), "+v"(W1), "+v"(W2), "+v"(W3),
                      "+v"(W4), "+v"(W5), "+v"(W6), "+v"(W7));
    asm volatile("" : "+v"(W8), "+v"(W9), "+v"(W10), "+v"(W11),
                      "+v"(W12), "+v"(W13), "+v"(W14), "+v"(W15));
    asm volatile("" : "+v"(W16), "+v"(W17), "+v"(W18), "+v"(W19),
                      "+v"(W20), "+v"(W21), "+v"(W22), "+v"(W23));
    asm volatile("" : "+v"(W24), "+v"(W25), "+v"(W26), "+v"(W27),
                      "+v"(W28), "+v"(W29), "+v"(W30), "+v"(W31));

    // ---- pointwise thread state (tid<256): biases in regs, c in a reg ----
    const int pw_L = tid >> 7, pw_idx = tid & 127, pw_b = (tid >> 3) & 15, pw_d = tid & 7;
    float bias_r[4] = {0.f, 0.f, 0.f, 0.f};
    float c_reg = 0.f;
    if (tid < 256) {
        const float* bi  = pw_L ? bih1 : bih0;
        const float* bh2 = pw_L ? bhh1 : bhh0;
#pragma unroll
        for (int g = 0; g < 4; ++g) {
            int row = g * 1024 + hg * 8 + pw_d;
            bias_r[g] = bi[row] + bh2[row];
        }
    }

    const int arow = bh * 16 + n;

#define MSTEP(AV, IA, IB) \
    acc0 = __builtin_amdgcn_mfma_f32_16x16x32_bf16(AV, __builtin_bit_cast(bf16x8_t, W##IA), acc0, 0, 0, 0); \
    acc1 = __builtin_amdgcn_mfma_f32_16x16x32_bf16(AV, __builtin_bit_cast(bf16x8_t, W##IB), acc1, 0, 0, 0)
#define CSTEP(KB, IA, IB) { \
    bf16x8_t av = *(const bf16x8_t*)(const void*)(a_base + (KB) * 32); \
    MSTEP(av, IA, IB); }
#define LSTEP(KB, IA, IB) { \
    union { u64 qq[2]; bf16x8_t v; } u_; \
    u_.qq[0] = hstage[kh][KB][lane][0]; \
    u_.qq[1] = hstage[kh][KB][lane][1]; \
    MSTEP(u_.v, IA, IB); }
#define FSTEP(KB, IA, IB) MSTEP(h1f[KB], IA, IB)

    for (int t = 0; t <= TT; ++t) {
        // ================= stage 1: fabric loads =================
        bf16x8_t h1f[16];
        if (L == 1 && p == 1) {
            // waves 6,7: prefetch h1(t-2) fragments into regs (latency overlaps staging)
            u64* ab = (u64*)(void*)((const __bf16*)h1buf + (size_t)(t & 1) * BH
                                    + arow * 1024 + kh * 512 + q * 8);
#pragma unroll
            for (int kb = 0; kb < 16; ++kb) {
                union { u64 qq[2]; bf16x8_t v; } u_;
                u_.qq[0] = __hip_atomic_load(ab + kb * 8,     __ATOMIC_RELAXED, __HIP_MEMORY_SCOPE_AGENT);
                u_.qq[1] = __hip_atomic_load(ab + kb * 8 + 1, __ATOMIC_RELAXED, __HIP_MEMORY_SCOPE_AGENT);
                h1f[kb] = u_.v;
            }
        } else if (p != L) {
            // waves 2,3 (L0 h-GEMM) + 4,5 (L1 x-GEMM): split-load h0(t-1), stage to LDS
            u64* hb = (u64*)(void*)((const __bf16*)h0buf + (size_t)((t + 1) & 1) * BH
                                    + arow * 1024 + kh * 512 + q * 8);
            const int s0 = (L == 0) ? 0 : 8;
#pragma unroll
            for (int s = 0; s < 8; ++s) {
                const int kb = s0 + s;
                u64 lo = __hip_atomic_load(hb + kb * 8,     __ATOMIC_RELAXED, __HIP_MEMORY_SCOPE_AGENT);
                u64 hi = __hip_atomic_load(hb + kb * 8 + 1, __ATOMIC_RELAXED, __HIP_MEMORY_SCOPE_AGENT);
                hstage[kh][kb][lane][0] = lo;
                hstage[kh][kb][lane][1] = hi;
            }
        }
        __syncthreads();   // hstage ready (also drains waves 6,7's prefetch vmcnt)

        // ================= stage 2: GEMMs =================
        f32x4_t acc0 = {0.f, 0.f, 0.f, 0.f};
        f32x4_t acc1 = {0.f, 0.f, 0.f, 0.f};
        if (L == 0 && p == 0) {
            // x-GEMM: cached loads (xbuf is read-only, L2/MALL-served)
            const __bf16* a_base = (const __bf16*)xb + (size_t)(t < TT ? t : TT - 1) * BH
                                   + arow * 1024 + kh * 512 + q * 8;
            CSTEP(0,0,16);  CSTEP(1,1,17);  CSTEP(2,2,18);  CSTEP(3,3,19);
            CSTEP(4,4,20);  CSTEP(5,5,21);  CSTEP(6,6,22);  CSTEP(7,7,23);
            CSTEP(8,8,24);  CSTEP(9,9,25);  CSTEP(10,10,26); CSTEP(11,11,27);
            CSTEP(12,12,28); CSTEP(13,13,29); CSTEP(14,14,30); CSTEP(15,15,31);
        } else if (p != L) {
            LSTEP(0,0,16);  LSTEP(1,1,17);  LSTEP(2,2,18);  LSTEP(3,3,19);
            LSTEP(4,4,20);  LSTEP(5,5,21);  LSTEP(6,6,22);  LSTEP(7,7,23);
            LSTEP(8,8,24);  LSTEP(9,9,25);  LSTEP(10,10,26); LSTEP(11,11,27);
            LSTEP(12,12,28); LSTEP(13,13,29); LSTEP(14,14,30); LSTEP(15,15,31);
        } else {
            FSTEP(0,0,16);  FSTEP(1,1,17);  FSTEP(2,2,18);  FSTEP(3,3,19);
            FSTEP(4,4,20);  FSTEP(5,5,21);  FSTEP(6,6,22);  FSTEP(7,7,23);
            FSTEP(8,8,24);  FSTEP(9,9,25);  FSTEP(10,10,26); FSTEP(11,11,27);
            FSTEP(12,12,28); FSTEP(13,13,29); FSTEP(14,14,30); FSTEP(15,15,31);
        }

        // C/D: lane holds D[i = q*4+r][j = n]
#pragma unroll
        for (int r = 0; r < 4; ++r) {
            psum[L][p][kh][q * 4 + r][n] = acc0[r];
            psum[L][p][kh][q * 4 + r][16 + n] = acc1[r];
        }
        __syncthreads();

        // ================= stage 3: pointwise =================
        if (tid < 256) {
            const bool active = pw_L ? (t >= 1) : (t < TT);
            if (active) {
                float gv[4];
#pragma unroll
                for (int g = 0; g < 4; ++g) {
                    int col = (g >> 1) * 16 + (g & 1) * 8 + pw_d;
                    gv[g] = psum[pw_L][0][0][pw_b][col] + psum[pw_L][0][1][pw_b][col]
                          + psum[pw_L][1][0][pw_b][col] + psum[pw_L][1][1][pw_b][col]
                          + bias_r[g];
                }
                float si = 1.f / (1.f + __expf(-gv[0]));
                float sf = 1.f / (1.f + __expf(-gv[1]));
                float tg = 2.f / (1.f + __expf(-2.f * gv[2])) - 1.f;
                float so = 1.f / (1.f + __expf(-gv[3]));
                c_reg = sf * c_reg + si * tg;
                float hv = so * (2.f / (1.f + __expf(-2.f * c_reg)) - 1.f);
                const int gidx = (bh * 16 + pw_b) * 1024 + hg * 8 + pw_d;
                __hip_bfloat16 hb16 = __float2bfloat16(hv);
                unsigned short hraw;
                __builtin_memcpy(&hraw, &hb16, 2);
                if (pw_L == 0) {
                    __hip_atomic_store((unsigned short*)&h0buf[(size_t)(t & 1) * BH + gidx],
                                       hraw, __ATOMIC_RELAXED, __HIP_MEMORY_SCOPE_AGENT);
                    res[t & 1][pw_idx] = hv;
                } else {
                    __hip_atomic_store((unsigned short*)&h1buf[(size_t)((t - 1) & 1) * BH + gidx],
                                       hraw, __ATOMIC_RELAXED, __HIP_MEMORY_SCOPE_AGENT);
                    out[(size_t)(bh * 16 + pw_b) * TT * HH + (size_t)(t - 1) * HH + hg * 8 + pw_d]
                        = res[(t + 1) & 1][pw_idx] + hv;
                }
            }
        }
        __syncthreads();   // drains vmcnt: h stores acked at coherence point before arrive

        // ================= stage 4: global barrier (RMW-free) =================
        if (t < TT) {
            const unsigned tgt = (unsigned)(t + 1);
            if (tid == 0)
                __hip_atomic_store(&arr[wg * 32], tgt, __ATOMIC_RELAXED, __HIP_MEMORY_SCOPE_AGENT);
            if (wg == 0) {
                if (tid < 256) {
                    while (__hip_atomic_load(&arr[tid * 32], __ATOMIC_RELAXED,
                                             __HIP_MEMORY_SCOPE_AGENT) < tgt)
                        __builtin_amdgcn_s_sleep(1);
                }
                __syncthreads();
                if (tid < 256)
                    __hip_atomic_store(&go[tid * 32], tgt, __ATOMIC_RELAXED, __HIP_MEMORY_SCOPE_AGENT);
            } else {
                if (tid == 0) {
                    while (__hip_atomic_load(&go[wg * 32], __ATOMIC_RELAXED,
                                             __HIP_MEMORY_SCOPE_AGENT) < tgt)
                        __builtin_amdgcn_s_sleep(1);
                }
            }
            __syncthreads();
        }
    }
#undef MSTEP
#undef CSTEP
#undef LSTEP
#undef FSTEP
}

// ---------------------------------------------------------------------------
// Host side
// ---------------------------------------------------------------------------
extern "C" void kernel_launch(void* const* d_in, const int* in_sizes, int n_in,
                              void* d_out, int out_size, void* d_ws, size_t ws_size,
                              hipStream_t stream) {
    const float* x    = (const float*)d_in[0];
    const float* Wih0 = (const float*)d_in[1];
    const float* Whh0 = (const float*)d_in[2];
    const float* bih0 = (const float*)d_in[3];
    const float* bhh0 = (const float*)d_in[4];
    const float* Wih1 = (const float*)d_in[5];
    const float* Whh1 = (const float*)d_in[6];
    const float* bih1 = (const float*)d_in[7];
    const float* bhh1 = (const float*)d_in[8];
    float* out = (float*)d_out;
    (void)in_sizes; (void)n_in; (void)out_size; (void)ws_size;

    // Workspace carve (~64.4 MiB)
    uint8_t* w = (uint8_t*)d_ws;
    const size_t WMAT = (size_t)G4H * HH * 2;   // 8 MiB bf16 per matrix
    __hip_bfloat16* Wxs0 = (__hip_bfloat16*)(w);
    __hip_bfloat16* Whs0 = (__hip_bfloat16*)(w + WMAT);
    __hip_bfloat16* Wxs1 = (__hip_bfloat16*)(w + 2 * WMAT);
    __hip_bfloat16* Whs1 = (__hip_bfloat16*)(w + 3 * WMAT);
    size_t off = 4 * WMAT;
    __hip_bfloat16* xbuf = (__hip_bfloat16*)(w + off); off += (size_t)TT * BB * II * 2;
    __hip_bfloat16* h0buf = (__hip_bfloat16*)(w + off); off += 2 * (size_t)BH * 2;
    __hip_bfloat16* h1buf = (__hip_bfloat16*)(w + off); off += 2 * (size_t)BH * 2;
    unsigned* arr = (unsigned*)(w + off); off += 8192 * 4;
    unsigned* go  = (unsigned*)(w + off); off += 8192 * 4;

    init_bufs<<<(2 * BH) / 256, 256, 0, stream>>>(h0buf, h1buf, arr, go);
    shuffle_w<<<(G4H * HH) / 256, 256, 0, stream>>>(Wih0, Wxs0);
    shuffle_w<<<(G4H * HH) / 256, 256, 0, stream>>>(Whh0, Whs0);
    shuffle_w<<<(G4H * HH) / 256, 256, 0, stream>>>(Wih1, Wxs1);
    shuffle_w<<<(G4H * HH) / 256, 256, 0, stream>>>(Whh1, Whs1);
    convert_x<<<(TT * BB * II) / 256, 256, 0, stream>>>(x, xbuf);

    lstm_persist<<<256, 512, 0, stream>>>(xbuf, Wxs0, Whs0, Wxs1, Whs1,
                                          bih0, bhh0, bih1, bhh1,
                                          h0buf, h1buf, out, arr, go);
}

// Round 5
// 3898.306 us; speedup vs baseline: 3.1065x; 1.1495x over previous
//
#include <hip/hip_runtime.h>
#include <hip/hip_bf16.h>

// Problem sizes (fixed)
#define BB 32
#define TT 512
#define HH 1024
#define II 1024
#define G4H 4096
#define BH  (BB * HH)          // 32768

typedef __bf16 bf16x8_t __attribute__((ext_vector_type(8)));
typedef float f32x4_t __attribute__((ext_vector_type(4)));
typedef int i32x4_t __attribute__((ext_vector_type(4)));
typedef unsigned long long u64;

// ---------------------------------------------------------------------------
// Zero rotating h buffers + arrive flags. (ws re-poisoned 0xAA each call)
// grid: 256 x 256 covers 65536 = 2*BH
// ---------------------------------------------------------------------------
__global__ void init_bufs(__hip_bfloat16* __restrict__ h0buf,
                          __hip_bfloat16* __restrict__ h1buf,
                          unsigned* __restrict__ arr) {
    int i = blockIdx.x * 256 + threadIdx.x;
    h0buf[i] = __float2bfloat16(0.f);
    h1buf[i] = __float2bfloat16(0.f);
    if (i < 8192) arr[i] = 0u;
}

// ---------------------------------------------------------------------------
// Weight shuffle: fp32 [4096][1024] -> bf16 B-fragment order.
// dst bits: jj:3 | lane:6 | kb:4 | kh:1 | tau:1 | hg:7
//   n=lane&15, q=lane>>4
//   row = (2*tau + (n>>3))*1024 + hg*8 + (n&7)
//   col = kh*512 + kb*32 + q*8 + jj
// ---------------------------------------------------------------------------
__global__ void shuffle_w(const float* __restrict__ src, __hip_bfloat16* __restrict__ dst) {
    size_t i = (size_t)blockIdx.x * 256 + threadIdx.x;   // 0 .. 4M-1
    int jj   = (int)(i & 7);
    int lane = (int)((i >> 3) & 63);
    int kb   = (int)((i >> 9) & 15);
    int kh   = (int)((i >> 13) & 1);
    int tau  = (int)((i >> 14) & 1);
    int hg   = (int)(i >> 15);
    int n = lane & 15, q = lane >> 4;
    int row = (2 * tau + (n >> 3)) * 1024 + hg * 8 + (n & 7);
    int col = kh * 512 + kb * 32 + q * 8 + jj;
    dst[i] = __float2bfloat16(src[(size_t)row * II + col]);
}

// ---------------------------------------------------------------------------
// x [B][T][I] fp32 -> xb [T][B][I] bf16
// ---------------------------------------------------------------------------
__global__ void convert_x(const float* __restrict__ x, __hip_bfloat16* __restrict__ xb) {
    size_t i = (size_t)blockIdx.x * 256 + threadIdx.x;   // T*B*I
    int ii = (int)(i & 1023);
    int b  = (int)((i >> 10) & 31);
    int t  = (int)(i >> 15);
    xb[i] = __float2bfloat16(x[((size_t)b * TT + t) * II + ii]);
}

// ---------------------------------------------------------------------------
// Persistent fused 2-layer LSTM. 256 WGs (1/CU) x 512 threads (8 waves).
// WG wg: bh = wg>>7 (batch half), hg = wg&127 (8 h-dims -> 32 gate rows).
// wave: L = w>>2 (layer), p = (w>>1)&1 (x- vs h-GEMM), kh = w&1 (K half).
// Weights pinned in VGPRs/AGPRs via empty-asm "+v" (32 x i32x4 per wave).
// Phase t = layer0@t + layer1@(t-1), skewed pipeline, 513 phases.
//
// Coherence protocol (fence-light):
//  - producers write h (and out) with cache-BYPASSING relaxed agent atomics;
//    the pre-barrier __syncthreads drains vmcnt, so h is at the coherence
//    point (IF) before the arrive flag is stored. NOTHING dirty lives in L2.
//  - all-to-all barrier within each bh-group of 128 WGs (the only WGs that
//    exchange data): 1 flag store/WG, 128 threads poll the 128 flags of own
//    group directly. No master round-trip.
//  - after the barrier, ONE buffer_inv sc0 sc1 per CU invalidates stale
//    L1/L2 lines; consumers then read h with PLAIN cached vector loads:
//    first touch per XCD misses to IF, the rest of the XCD hits L2/L1.
//    (safe: no dirty lines to drop, all dirty data bypassed the caches)
// ---------------------------------------------------------------------------
__global__ __launch_bounds__(512, 2)
void lstm_persist(const __hip_bfloat16* __restrict__ xb,
                  const __hip_bfloat16* __restrict__ Wxs0, const __hip_bfloat16* __restrict__ Whs0,
                  const __hip_bfloat16* __restrict__ Wxs1, const __hip_bfloat16* __restrict__ Whs1,
                  const float* __restrict__ bih0, const float* __restrict__ bhh0,
                  const float* __restrict__ bih1, const float* __restrict__ bhh1,
                  __hip_bfloat16* __restrict__ h0buf,   // [2][BH] rotating
                  __hip_bfloat16* __restrict__ h1buf,   // [2][BH] rotating
                  float* __restrict__ out,              // [B][T][H]
                  unsigned* __restrict__ arr)           // [256][32] arrive flags
{
    const int wg = blockIdx.x, tid = threadIdx.x;
    const int bh = wg >> 7, hg = wg & 127;
    const int wave = tid >> 6, lane = tid & 63;
    const int L = wave >> 2, p = (wave >> 1) & 1, kh = wave & 1;
    const int n = lane & 15, q = lane >> 4;

    __shared__ float psum[2][2][2][16][37];   // [L][p][kh][batch][tau*16+n]; pad 37:
                                              // MFMA writes 2-way (free), pointwise reads conflict-free
    __shared__ float res[2][128];             // fp32 h0 hand-off for residual

    // ---- load B-fragments once, pin in registers ----
    const __hip_bfloat16* Wsel = L ? (p ? Whs1 : Wxs1) : (p ? Whs0 : Wxs0);
    const __bf16* wbp = (const __bf16*)Wsel;

    i32x4_t W0, W1, W2, W3, W4, W5, W6, W7, W8, W9, W10, W11, W12, W13, W14, W15,
            W16, W17, W18, W19, W20, W21, W22, W23, W24, W25, W26, W27, W28, W29, W30, W31;
#define LOADW(IDX, TAU, KB) \
    W##IDX = *(const i32x4_t*)(const void*)(wbp + ((((((size_t)hg * 2 + (TAU)) * 2 + kh) * 16) + (KB)) * 64 + lane) * 8)
    LOADW(0,0,0);  LOADW(1,0,1);  LOADW(2,0,2);  LOADW(3,0,3);
    LOADW(4,0,4);  LOADW(5,0,5);  LOADW(6,0,6);  LOADW(7,0,7);
    LOADW(8,0,8);  LOADW(9,0,9);  LOADW(10,0,10); LOADW(11,0,11);
    LOADW(12,0,12); LOADW(13,0,13); LOADW(14,0,14); LOADW(15,0,15);
    LOADW(16,1,0);  LOADW(17,1,1);  LOADW(18,1,2);  LOADW(19,1,3);
    LOADW(20,1,4);  LOADW(21,1,5);  LOADW(22,1,6);  LOADW(23,1,7);
    LOADW(24,1,8);  LOADW(25,1,9);  LOADW(26,1,10); LOADW(27,1,11);
    LOADW(28,1,12); LOADW(29,1,13); LOADW(30,1,14); LOADW(31,1,15);
#undef LOADW
    // Opaque-ify: forbids rematerializing these loads inside the phase loop.
    asm volatile("" : "+v"(W0), "+v"(W1), "+v"(W2), "+v"(W3),
                      "+v"(W4), "+v"(W5), "+v"(W6), "+v"(W7));
    asm volatile("" : "+v"(W8), "+v"(W9), "+v"(W10), "+v"(W11),
                      "+v"(W12), "+v"(W13), "+v"(W14), "+v"(W15));
    asm volatile("" : "+v"(W16), "+v"(W17), "+v"(W18), "+v"(W19),
                      "+v"(W20), "+v"(W21), "+v"(W22), "+v"(W23));
    asm volatile("" : "+v"(W24), "+v"(W25), "+v"(W26), "+v"(W27),
                      "+v"(W28), "+v"(W29), "+v"(W30), "+v"(W31));

    // ---- pointwise thread state (tid<256): biases in regs, c in a reg ----
    const int pw_L = tid >> 7, pw_idx = tid & 127, pw_b = (tid >> 3) & 15, pw_d = tid & 7;
    float bias_r[4] = {0.f, 0.f, 0.f, 0.f};
    float c_reg = 0.f;
    if (tid < 256) {
        const float* bi  = pw_L ? bih1 : bih0;
        const float* bh2 = pw_L ? bhh1 : bhh0;
#pragma unroll
        for (int g = 0; g < 4; ++g) {
            int row = g * 1024 + hg * 8 + pw_d;
            bias_r[g] = bi[row] + bh2[row];
        }
    }

    const int arow = bh * 16 + n;
    // poll target line: my bh-group's WG (bh*128 + tid), threads 0..127
    const unsigned* poll_line = &arr[(size_t)(bh * 128 + (tid & 127)) * 32];

#define MSTEP(AV, IA, IB) \
    acc0 = __builtin_amdgcn_mfma_f32_16x16x32_bf16(AV, __builtin_bit_cast(bf16x8_t, W##IA), acc0, 0, 0, 0); \
    acc1 = __builtin_amdgcn_mfma_f32_16x16x32_bf16(AV, __builtin_bit_cast(bf16x8_t, W##IB), acc1, 0, 0, 0)
#define CSTEP(KB, IA, IB) { \
    bf16x8_t av = *(const bf16x8_t*)(const void*)(a_base + (KB) * 32); \
    MSTEP(av, IA, IB); }

    for (int t = 0; t <= TT; ++t) {
        // ================= stage 1: GEMMs (plain cached loads; L2 dedups bcast) ====
        const __hip_bfloat16* Abuf;
        if (L == 0) {
            Abuf = p ? (h0buf + (size_t)((t + 1) & 1) * BH)
                     : (xb + (size_t)(t < TT ? t : TT - 1) * BH);
        } else {
            Abuf = p ? (h1buf + (size_t)(t & 1) * BH)
                     : (h0buf + (size_t)((t + 1) & 1) * BH);
        }
        const __bf16* a_base = (const __bf16*)Abuf + arow * 1024 + kh * 512 + q * 8;

        f32x4_t acc0 = {0.f, 0.f, 0.f, 0.f};
        f32x4_t acc1 = {0.f, 0.f, 0.f, 0.f};
        CSTEP(0,0,16);  CSTEP(1,1,17);  CSTEP(2,2,18);  CSTEP(3,3,19);
        CSTEP(4,4,20);  CSTEP(5,5,21);  CSTEP(6,6,22);  CSTEP(7,7,23);
        CSTEP(8,8,24);  CSTEP(9,9,25);  CSTEP(10,10,26); CSTEP(11,11,27);
        CSTEP(12,12,28); CSTEP(13,13,29); CSTEP(14,14,30); CSTEP(15,15,31);

        // C/D: lane holds D[i = q*4+r][j = n]
#pragma unroll
        for (int r = 0; r < 4; ++r) {
            psum[L][p][kh][q * 4 + r][n] = acc0[r];
            psum[L][p][kh][q * 4 + r][16 + n] = acc1[r];
        }
        __syncthreads();

        // ================= stage 2: pointwise =================
        if (tid < 256) {
            const bool active = pw_L ? (t >= 1) : (t < TT);
            if (active) {
                float gv[4];
#pragma unroll
                for (int g = 0; g < 4; ++g) {
                    int col = (g >> 1) * 16 + (g & 1) * 8 + pw_d;
                    gv[g] = psum[pw_L][0][0][pw_b][col] + psum[pw_L][0][1][pw_b][col]
                          + psum[pw_L][1][0][pw_b][col] + psum[pw_L][1][1][pw_b][col]
                          + bias_r[g];
                }
                float si = 1.f / (1.f + __expf(-gv[0]));
                float sf = 1.f / (1.f + __expf(-gv[1]));
                float tg = 2.f / (1.f + __expf(-2.f * gv[2])) - 1.f;
                float so = 1.f / (1.f + __expf(-gv[3]));
                c_reg = sf * c_reg + si * tg;
                float hv = so * (2.f / (1.f + __expf(-2.f * c_reg)) - 1.f);
                const int gidx = (bh * 16 + pw_b) * 1024 + hg * 8 + pw_d;
                __hip_bfloat16 hb16 = __float2bfloat16(hv);
                unsigned short hraw;
                __builtin_memcpy(&hraw, &hb16, 2);
                if (pw_L == 0) {
                    __hip_atomic_store((unsigned short*)&h0buf[(size_t)(t & 1) * BH + gidx],
                                       hraw, __ATOMIC_RELAXED, __HIP_MEMORY_SCOPE_AGENT);
                    res[t & 1][pw_idx] = hv;
                } else {
                    __hip_atomic_store((unsigned short*)&h1buf[(size_t)((t - 1) & 1) * BH + gidx],
                                       hraw, __ATOMIC_RELAXED, __HIP_MEMORY_SCOPE_AGENT);
                    // out store also bypasses L2 (keeps L2 clean for buffer_inv)
                    __hip_atomic_store(&out[(size_t)(bh * 16 + pw_b) * TT * HH
                                            + (size_t)(t - 1) * HH + hg * 8 + pw_d],
                                       res[(t + 1) & 1][pw_idx] + hv,
                                       __ATOMIC_RELAXED, __HIP_MEMORY_SCOPE_AGENT);
                }
            }
        }
        __syncthreads();   // drains vmcnt: h stores acked at coherence point before arrive

        // ================= stage 3: all-to-all barrier within bh-group ============
        if (t < TT) {
            const unsigned tgt = (unsigned)(t + 1);
            if (tid == 0)
                __hip_atomic_store(&arr[(size_t)wg * 32], tgt,
                                   __ATOMIC_RELAXED, __HIP_MEMORY_SCOPE_AGENT);
            if (tid < 128) {
                while (__hip_atomic_load(poll_line, __ATOMIC_RELAXED,
                                         __HIP_MEMORY_SCOPE_AGENT) < tgt)
                    __builtin_amdgcn_s_sleep(1);
            }
            __syncthreads();
            // one L1+L2 invalidate per CU; safe: no dirty lines in cache
            if (wave == 0)
                asm volatile("buffer_inv sc0 sc1\n\ts_waitcnt vmcnt(0)" ::: "memory");
            __syncthreads();   // inv complete before any wave's cached h loads
        }
    }
#undef MSTEP
#undef CSTEP
}

// ---------------------------------------------------------------------------
// Host side
// ---------------------------------------------------------------------------
extern "C" void kernel_launch(void* const* d_in, const int* in_sizes, int n_in,
                              void* d_out, int out_size, void* d_ws, size_t ws_size,
                              hipStream_t stream) {
    const float* x    = (const float*)d_in[0];
    const float* Wih0 = (const float*)d_in[1];
    const float* Whh0 = (const float*)d_in[2];
    const float* bih0 = (const float*)d_in[3];
    const float* bhh0 = (const float*)d_in[4];
    const float* Wih1 = (const float*)d_in[5];
    const float* Whh1 = (const float*)d_in[6];
    const float* bih1 = (const float*)d_in[7];
    const float* bhh1 = (const float*)d_in[8];
    float* out = (float*)d_out;
    (void)in_sizes; (void)n_in; (void)out_size; (void)ws_size;

    // Workspace carve (~64.4 MiB)
    uint8_t* w = (uint8_t*)d_ws;
    const size_t WMAT = (size_t)G4H * HH * 2;   // 8 MiB bf16 per matrix
    __hip_bfloat16* Wxs0 = (__hip_bfloat16*)(w);
    __hip_bfloat16* Whs0 = (__hip_bfloat16*)(w + WMAT);
    __hip_bfloat16* Wxs1 = (__hip_bfloat16*)(w + 2 * WMAT);
    __hip_bfloat16* Whs1 = (__hip_bfloat16*)(w + 3 * WMAT);
    size_t off = 4 * WMAT;
    __hip_bfloat16* xbuf = (__hip_bfloat16*)(w + off); off += (size_t)TT * BB * II * 2;
    __hip_bfloat16* h0buf = (__hip_bfloat16*)(w + off); off += 2 * (size_t)BH * 2;
    __hip_bfloat16* h1buf = (__hip_bfloat16*)(w + off); off += 2 * (size_t)BH * 2;
    unsigned* arr = (unsigned*)(w + off); off += 8192 * 4;

    init_bufs<<<(2 * BH) / 256, 256, 0, stream>>>(h0buf, h1buf, arr);
    shuffle_w<<<(G4H * HH) / 256, 256, 0, stream>>>(Wih0, Wxs0);
    shuffle_w<<<(G4H * HH) / 256, 256, 0, stream>>>(Whh0, Whs0);
    shuffle_w<<<(G4H * HH) / 256, 256, 0, stream>>>(Wih1, Wxs1);
    shuffle_w<<<(G4H * HH) / 256, 256, 0, stream>>>(Whh1, Whs1);
    convert_x<<<(TT * BB * II) / 256, 256, 0, stream>>>(x, xbuf);

    lstm_persist<<<256, 512, 0, stream>>>(xbuf, Wxs0, Whs0, Wxs1, Whs1,
                                          bih0, bhh0, bih1, bhh1,
                                          h0buf, h1buf, out, arr);
}